// Round 21
// baseline (216.632 us; speedup 1.0000x reference)
//
#include <hip/hip_runtime.h>
#include <hip/hip_fp16.h>

#define NQ 32768           // total queries = 8192 positions * K=4
#define NCODES 16384
#define ZQ_ELEMS 2097152   // 8*256*32*32
#define IDX_OFF ZQ_ELEMS
#define LOSS_OFF (ZQ_ELEMS + NQ)
// 256 chunks of 64 codes each; chunkmax: fp16 (round-up) [query][256] = 16 MB
// bf16 buffers in MFMA-fragment order: [tile=row/32][kc=d/16][lh=(d>>3)&1][l31=row&31][j=d&7]

typedef __attribute__((ext_vector_type(8))) short short8;
typedef __attribute__((ext_vector_type(16))) float float16;

// query id j = b*4096 + i*1024 + hw ; z element (j,d) at (b<<18) + (d<<12) + (i<<10) + hw

__device__ __forceinline__ unsigned short to_bf16(float v) {
    unsigned u = __float_as_uint(v);
    u = u + 0x7FFFu + ((u >> 16) & 1u);          // round-to-nearest-even
    return (unsigned short)(u >> 16);
}

// f32 -> f16 bits, rounded UP (result as float >= x).
__device__ __forceinline__ unsigned short f16_ru(float x) {
    __half h = __float2half(x);                  // RNE
    unsigned short u = __half_as_ushort(h);
    if (__half2float(h) < x) {
        if (u & 0x8000) u = (u == 0x8000) ? (unsigned short)0x0001 : (unsigned short)(u - 1);
        else u = (unsigned short)(u + 1);
    }
    return u;
}

// Fused prep: z transpose -> swizzled bf16 hi (coalesced short8 stores),
// znorm + sum|z|, emb -> swizzled bf16 hi.
__global__ void __launch_bounds__(256)
prep_kernel(const float* __restrict__ z, const float* __restrict__ emb,
            unsigned short* __restrict__ zhi, unsigned short* __restrict__ ehi,
            float* __restrict__ znorm, float* __restrict__ sabs, float* __restrict__ out) {
    __shared__ float tile[64][65];
    int t = threadIdx.x;
    if (blockIdx.x == 0 && t == 0) out[LOSS_OFF] = 0.f;
    int q0 = blockIdx.x * 64;
    int base = ((q0 >> 12) << 18) + (q0 & 4095);
    int qo = t & 63, dp = t >> 6;
#pragma unroll
    for (int dd = 0; dd < 16; ++dd) {
        int d = dd * 4 + dp;
        tile[d][qo] = z[base + (d << 12) + qo];
    }
    __syncthreads();
    // zhi writes: 512 units = 64 queries x 8 (kc,lh) groups; thread t does units t, t+256.
    size_t ztbase = (size_t)q0 * 64;   // = (q0/32)*2048
#pragma unroll
    for (int uu = 0; uu < 2; ++uu) {
        int unit = uu * 256 + t;
        int q = unit & 63;
        int m = unit >> 6;
        short8 sv;
#pragma unroll
        for (int j = 0; j < 8; ++j)
            sv[j] = (short)to_bf16(tile[m * 8 + j][q]);
        int Q = q0 + q;
        *reinterpret_cast<short8*>(zhi + ztbase + (size_t)(q >> 5) * 2048
                                   + (size_t)m * 256 + (size_t)(Q & 31) * 8) = sv;
    }
    if (t < 64) {
        double s = 0.0, sa = 0.0;
#pragma unroll
        for (int d2 = 0; d2 < 64; ++d2) {
            float v = tile[d2][t];
            s += (double)v * (double)v;
            sa += fabs((double)v);
        }
        znorm[q0 + t] = (float)s;
        sabs[q0 + t] = (float)(sa * 1.000001 + 1e-6);   // strict upper bound on sum|z|
    }
    // emb: one 8-dim block per thread; 512 blocks x 256 units = NCODES*8 units
    {
        int u = blockIdx.x * 256 + t;
        int code = u >> 3, db = u & 7;
        const float4* ep = reinterpret_cast<const float4*>(emb + (size_t)code * 64 + db * 8);
        float4 v0 = ep[0], v1 = ep[1];
        float vv[8] = {v0.x, v0.y, v0.z, v0.w, v1.x, v1.y, v1.z, v1.w};
        short8 h8;
#pragma unroll
        for (int j = 0; j < 8; ++j) h8[j] = (short)to_bf16(vv[j]);
        size_t wi = (size_t)(code >> 5) * 2048 + (size_t)(db >> 1) * 512
                  + (size_t)(db & 1) * 256 + (size_t)(code & 31) * 8;
        *reinterpret_cast<short8*>(ehi + wi) = h8;
    }
}

__device__ __forceinline__ unsigned long long pack_min(float f, int idx) {
    unsigned u = __float_as_uint(f);
    unsigned s = (u & 0x80000000u) ? ~u : (u | 0x80000000u);
    return ((unsigned long long)s << 32) | (unsigned)idx;
}

__device__ __forceinline__ float tmax16(float16 a) {   // max3-friendly tree
    float x0 = fmaxf(a[0], fmaxf(a[1], a[2]));
    float x1 = fmaxf(a[3], fmaxf(a[4], a[5]));
    float x2 = fmaxf(a[6], fmaxf(a[7], a[8]));
    float x3 = fmaxf(a[9], fmaxf(a[10], a[11]));
    float x4 = fmaxf(a[12], fmaxf(a[13], a[14]));
    float y0 = fmaxf(x0, fmaxf(x1, x2));
    float y1 = fmaxf(x3, fmaxf(x4, a[15]));
    return fmaxf(y0, y1);
}

// Pass 1: single hi*hi bf16 MFMA; per-64-code chunk maxima stored as round-up fp16.
// 4 query-groups x 1 code-tile; grid (64 qblocks, 32 slabs) x 256.
__global__ void __launch_bounds__(256, 2)
approx_kernel(const unsigned short* __restrict__ zhi, const unsigned short* __restrict__ ehi,
              unsigned short* __restrict__ chunkmax) {
    int t = threadIdx.x;
    int lane = t & 63;
    int w = t >> 6;
    int qw = blockIdx.x * 512 + w * 128;
    int cbase = blockIdx.y * 512;
    int l31 = lane & 31, lh = lane >> 5;

    short8 qh[4][4];
    {
        size_t qbase = (size_t)qw * 64 + (size_t)lane * 8;
#pragma unroll
        for (int g = 0; g < 4; ++g)
#pragma unroll
            for (int kc = 0; kc < 4; ++kc)
                qh[g][kc] = *(const short8*)(zhi + qbase + g * 2048 + kc * 512);
    }

#pragma unroll 2
    for (int c64 = 0; c64 < 8; ++c64) {    // 64-code chunk per iter
        float m0 = -3.4e38f, m1 = -3.4e38f, m2 = -3.4e38f, m3 = -3.4e38f;
#pragma unroll
        for (int tl = 0; tl < 2; ++tl) {   // 32 codes per tile
            size_t abase = (size_t)(cbase + c64 * 64 + tl * 32) * 64 + (size_t)lane * 8;
            short8 ch[4];
#pragma unroll
            for (int kc = 0; kc < 4; ++kc)
                ch[kc] = *(const short8*)(ehi + abase + kc * 512);
            float16 a0 = (float16)(0.0f), a1 = (float16)(0.0f);
            float16 a2 = (float16)(0.0f), a3 = (float16)(0.0f);
#pragma unroll
            for (int kc = 0; kc < 4; ++kc) {
                a0 = __builtin_amdgcn_mfma_f32_32x32x16_bf16(ch[kc], qh[0][kc], a0, 0, 0, 0);
                a1 = __builtin_amdgcn_mfma_f32_32x32x16_bf16(ch[kc], qh[1][kc], a1, 0, 0, 0);
                a2 = __builtin_amdgcn_mfma_f32_32x32x16_bf16(ch[kc], qh[2][kc], a2, 0, 0, 0);
                a3 = __builtin_amdgcn_mfma_f32_32x32x16_bf16(ch[kc], qh[3][kc], a3, 0, 0, 0);
            }
            m0 = fmaxf(m0, tmax16(a0));
            m1 = fmaxf(m1, tmax16(a1));
            m2 = fmaxf(m2, tmax16(a2));
            m3 = fmaxf(m3, tmax16(a3));
        }
        m0 = fmaxf(m0, __shfl_xor(m0, 32, 64));
        m1 = fmaxf(m1, __shfl_xor(m1, 32, 64));
        m2 = fmaxf(m2, __shfl_xor(m2, 32, 64));
        m3 = fmaxf(m3, __shfl_xor(m3, 32, 64));
        int chunkid = blockIdx.y * 8 + c64;
        if (lh == 0) {
            chunkmax[(size_t)(qw + l31) * 256 + chunkid] = f16_ru(m0);
            chunkmax[(size_t)(qw + 32 + l31) * 256 + chunkid] = f16_ru(m1);
            chunkmax[(size_t)(qw + 64 + l31) * 256 + chunkid] = f16_ru(m2);
            chunkmax[(size_t)(qw + 96 + l31) * 256 + chunkid] = f16_ru(m3);
        }
    }
}

// pop next qualifying chunk id (wave-uniform masks) or -1
#define POPNEXT(c) {                                                            \
    if (m0q) { c = __ffsll((long long)m0q) - 1; m0q &= m0q - 1; }               \
    else if (m1q) { c = 64 + __ffsll((long long)m1q) - 1; m1q &= m1q - 1; }     \
    else if (m2q) { c = 128 + __ffsll((long long)m2q) - 1; m2q &= m2q - 1; }    \
    else if (m3q) { c = 192 + __ffsll((long long)m3q) - 1; m3q &= m3q - 1; }    \
    else c = -1; }

// exact numpy-SSE 16-elem group: code elems Ea..Ed, query floats qp[qo..qo+3]
#define SGROUP(Ea, Eb, Ec, Ed, qo)                                              \
    g0 = qp[qo]; g1 = qp[qo + 1]; g2 = qp[qo + 2]; g3 = qp[qo + 3];             \
    A0 = Ea.x * g0.x + (Eb.x * g1.x + (Ec.x * g2.x + (Ed.x * g3.x + A0)));      \
    A1 = Ea.y * g0.y + (Eb.y * g1.y + (Ec.y * g2.y + (Ed.y * g3.y + A1)));      \
    A2 = Ea.z * g0.z + (Eb.z * g1.z + (Ec.z * g2.z + (Ed.z * g3.z + A2)));      \
    A3 = Ea.w * g0.w + (Eb.w * g1.w + (Ec.w * g2.w + (Ed.w * g3.w + A3)));

// exact SSE distance from E0..E15 into DRES
#define COMPUTE_D(DRES) {                                                       \
    _Pragma("clang fp contract(off)")                                           \
    float A0 = 0.f, A1 = 0.f, A2 = 0.f, A3 = 0.f;                               \
    float4 g0, g1, g2, g3;                                                      \
    SGROUP(E0, E1, E2, E3, 0)                                                   \
    SGROUP(E4, E5, E6, E7, 4)                                                   \
    SGROUP(E8, E9, E10, E11, 8)                                                 \
    SGROUP(E12, E13, E14, E15, 12)                                              \
    float dot = (A0 + A1) + (A2 + A3);   /* SSE3 hadd order */                  \
    DRES = zn - (dot + dot);             /* fl(znorm - 2*dot) */                \
}

// Stage chunk C (16 KB, 64 codes x 16 f4) into this wave's padded LDS region.
#define STAGE_CHUNK(C)                                                          \
    _Pragma("unroll")                                                           \
    for (int j = 0; j < 16; ++j) {                                              \
        int g = j * 64 + lane;                                                  \
        float4 v = emb4[(size_t)(C) * 1024 + g];                                \
        mye[(g >> 4) * 17 + (g & 15)] = v;                                      \
    }

#define READ_ROW {                                                              \
    const float4* rp = mye + lane * 17;                                         \
    E0 = rp[0];  E1 = rp[1];  E2 = rp[2];  E3 = rp[3];                          \
    E4 = rp[4];  E5 = rp[5];  E6 = rp[6];  E7 = rp[7];                          \
    E8 = rp[8];  E9 = rp[9];  E10 = rp[10]; E11 = rp[11];                       \
    E12 = rp[12]; E13 = rp[13]; E14 = rp[14]; E15 = rp[15]; }

// Pass 2: one wave per query, 128-thread blocks (2 waves). Exact-scan the argmax
// chunk first -> D; D-anchored threshold; LDS-staged exact scans of remaining
// qualifying chunks.
__global__ void __launch_bounds__(128, 2)
rescore_kernel(const float* __restrict__ z, const float* __restrict__ emb,
               const float* __restrict__ znorm, const float* __restrict__ sabs,
               const unsigned short* __restrict__ chunkmax,
               unsigned long long* __restrict__ best) {
    __shared__ float lds_q[2 * 64];
    __shared__ float4 lds_e[2 * 64 * 17];   // per wave: 64 rows x (16 f4 + 1 pad)
    int t = threadIdx.x;
    int lane = t & 63;
    int w = t >> 6;
    int qb = blockIdx.x * 2;
    int q = qb + w;

    if (t < 64) {   // queries qb, qb+1 are adjacent floats in z (same d-plane)
        int base0 = ((qb >> 12) << 18) + (qb & 4095);
        float2 vv = *reinterpret_cast<const float2*>(z + base0 + (t << 12));
        lds_q[t] = vv.x;
        lds_q[64 + t] = vv.y;
    }
    __syncthreads();

    float zn = znorm[q];
    float sa = sabs[q];

    const unsigned short* cmq = chunkmax + (size_t)q * 256;
    float ca = __half2float(__ushort_as_half(cmq[lane]));
    float cb = __half2float(__ushort_as_half(cmq[64 + lane]));
    float cc2 = __half2float(__ushort_as_half(cmq[128 + lane]));
    float cd = __half2float(__ushort_as_half(cmq[192 + lane]));
    float m = fmaxf(fmaxf(ca, cb), fmaxf(cc2, cd));
#pragma unroll
    for (int k = 32; k > 0; k >>= 1) m = fmaxf(m, __shfl_xor(m, k, 64));

    // locate one chunk achieving m
    unsigned long long ba = __ballot(ca == m);
    unsigned long long bb = __ballot(cb == m);
    unsigned long long bc = __ballot(cc2 == m);
    unsigned long long bd = __ballot(cd == m);
    int cm_id;
    if (ba) cm_id = __ffsll((long long)ba) - 1;
    else if (bb) cm_id = 64 + __ffsll((long long)bb) - 1;
    else if (bc) cm_id = 128 + __ffsll((long long)bc) - 1;
    else cm_id = 192 + __ffsll((long long)bd) - 1;

    const float4* qp = reinterpret_cast<const float4*>(lds_q + w * 64);
    const float4* emb4 = reinterpret_cast<const float4*>(emb);
    float4* mye = lds_e + w * (64 * 17);

    unsigned long long bloc;
    float4 E0,E1,E2,E3,E4,E5,E6,E7,E8,E9,E10,E11,E12,E13,E14,E15;

    // exact scan of the argmax chunk -> D
    float dmin;
    {
        STAGE_CHUNK(cm_id)
        READ_ROW
        float dres;
        COMPUTE_D(dres)
        bloc = pack_min(dres, cm_id * 64 + lane);
        dmin = dres;
#pragma unroll
        for (int k = 32; k > 0; k >>= 1) dmin = fminf(dmin, __shfl_xor(dmin, k, 64));
    }

    unsigned zb = __float_as_uint(zn);
    int ex = (int)((zb >> 23) & 0xFF);
    float g = __uint_as_float((unsigned)(ex - 23) << 23);   // ulp(zn)
    // D-anchored: t_j >= 0.5(zn-D) - g/2 for any possible winner; E <= 3e-7*sum|z|
    float thr = 0.5f * (zn - dmin) - 0.5f * g - 3e-7f * sa - 2e-6f;

    unsigned long long m0q = __ballot(ca >= thr);
    unsigned long long m1q = __ballot(cb >= thr);
    unsigned long long m2q = __ballot(cc2 >= thr);
    unsigned long long m3q = __ballot(cd >= thr);
    // exclude the already-scanned argmax chunk
    if (cm_id < 64)       m0q &= ~(1ull << cm_id);
    else if (cm_id < 128) m1q &= ~(1ull << (cm_id - 64));
    else if (cm_id < 192) m2q &= ~(1ull << (cm_id - 128));
    else                  m3q &= ~(1ull << (cm_id - 192));

    int cc; POPNEXT(cc);
    while (cc >= 0) {
        STAGE_CHUNK(cc)
        READ_ROW
        float dres;
        COMPUTE_D(dres)
        unsigned long long p = pack_min(dres, cc * 64 + lane);
        if (p < bloc) bloc = p;
        POPNEXT(cc);
    }

#pragma unroll
    for (int k = 32; k > 0; k >>= 1) {
        unsigned long long o = __shfl_xor(bloc, k, 64);
        if (o < bloc) bloc = o;
    }
    if (lane == 0) best[q] = bloc;
}

// Finalize, fully coalesced: 64 queries/block. Wave-parallel emb row gather
// (lane = dim, 4 lines/row) -> padded LDS; transpose-style write phase
// (thread = query, d-loop) identical in shape to prep's proven z access.
__global__ void __launch_bounds__(256)
finalize_kernel(const float* __restrict__ z, const float* __restrict__ emb,
                const unsigned long long* __restrict__ best,
                float* __restrict__ out) {
    __shared__ float tile[64][65];   // [q-local][d]
    __shared__ int idxs[64];
    __shared__ float red[256];
    int t = threadIdx.x;
    int lane = t & 63, w = t >> 6;
    int q0 = blockIdx.x * 64;

    if (t < 64) {
        int idx = (int)(unsigned)(best[q0 + t] & 0xFFFFFFFFull) & (NCODES - 1);
        idxs[t] = idx;
        out[IDX_OFF + q0 + t] = (float)idx;
    }
    __syncthreads();
    // each wave stages 16 winner rows: lanes read 64 consecutive floats
#pragma unroll
    for (int rr = 0; rr < 16; ++rr) {
        int r = rr * 4 + w;
        tile[r][lane] = emb[(size_t)idxs[r] * 64 + lane];
    }
    __syncthreads();
    // write z_q + loss: thread (qo, dp); d = dd*4+dp; coalesced across qo
    int base = ((q0 >> 12) << 18) + (q0 & 4095);
    int qo = t & 63, dp = t >> 6;
    float ls = 0.f;
#pragma unroll
    for (int dd = 0; dd < 16; ++dd) {
        int d = dd * 4 + dp;
        float ev = tile[qo][d];
        float zv = z[base + (d << 12) + qo];
        float r = ev - zv;
        ls += r * r;
        out[base + (d << 12) + qo] = ev;
    }
    red[t] = ls;
    __syncthreads();
    for (int off = 128; off > 0; off >>= 1) {
        if (t < off) red[t] += red[t + off];
        __syncthreads();
    }
    if (t == 0) atomicAdd(&out[LOSS_OFF], red[0] * (1.25f / 2097152.f));
}

extern "C" void kernel_launch(void* const* d_in, const int* in_sizes, int n_in,
                              void* d_out, int out_size, void* d_ws, size_t ws_size,
                              hipStream_t stream) {
    const float* z = (const float*)d_in[0];
    const float* emb = (const float*)d_in[1];
    float* out = (float*)d_out;

    char* ws = (char*)d_ws;
    unsigned long long* best = (unsigned long long*)ws;                 // 256 KB @0
    float* znorm = (float*)(ws + 262144);                               // 128 KB
    float* sabs = (float*)(ws + 393216);                                // 128 KB
    unsigned short* chunkmax = (unsigned short*)(ws + 524288);          // 16 MB fp16 [q][256]
    unsigned short* zhi = (unsigned short*)(ws + 17301504);             // 4 MB (swizzled)
    unsigned short* ehi = (unsigned short*)(ws + 21495808);             // 2 MB (total ~23.6 MB)

    prep_kernel<<<NQ / 64, 256, 0, stream>>>(z, emb, zhi, ehi, znorm, sabs, out);
    approx_kernel<<<dim3(64, 32), 256, 0, stream>>>(zhi, ehi, chunkmax);
    rescore_kernel<<<NQ / 2, 128, 0, stream>>>(z, emb, znorm, sabs, chunkmax, best);
    finalize_kernel<<<NQ / 64, 256, 0, stream>>>(z, emb, best, out);
}

// Round 22
// 206.817 us; speedup vs baseline: 1.0475x; 1.0475x over previous
//
#include <hip/hip_runtime.h>
#include <hip/hip_fp16.h>

#define NQ 32768           // total queries = 8192 positions * K=4
#define NCODES 16384
#define ZQ_ELEMS 2097152   // 8*256*32*32
#define IDX_OFF ZQ_ELEMS
#define LOSS_OFF (ZQ_ELEMS + NQ)
// 256 chunks of 64 codes each; chunkmax: fp16 (round-up) [query][256] = 16 MB
// bf16 buffers in MFMA-fragment order: [tile=row/32][kc=d/16][lh=(d>>3)&1][l31=row&31][j=d&7]

typedef __attribute__((ext_vector_type(8))) short short8;
typedef __attribute__((ext_vector_type(16))) float float16;

// query id j = b*4096 + i*1024 + hw ; z element (j,d) at (b<<18) + (d<<12) + (i<<10) + hw

__device__ __forceinline__ unsigned short to_bf16(float v) {
    unsigned u = __float_as_uint(v);
    u = u + 0x7FFFu + ((u >> 16) & 1u);          // round-to-nearest-even
    return (unsigned short)(u >> 16);
}

// f32 -> f16 bits, rounded UP (result as float >= x).
__device__ __forceinline__ unsigned short f16_ru(float x) {
    __half h = __float2half(x);                  // RNE
    unsigned short u = __half_as_ushort(h);
    if (__half2float(h) < x) {
        if (u & 0x8000) u = (u == 0x8000) ? (unsigned short)0x0001 : (unsigned short)(u - 1);
        else u = (unsigned short)(u + 1);
    }
    return u;
}

// Fused prep: z transpose -> swizzled bf16 hi (coalesced short8 stores),
// znorm + sum|z| (parallel fp64 partials), emb -> swizzled bf16 hi.
__global__ void __launch_bounds__(256)
prep_kernel(const float* __restrict__ z, const float* __restrict__ emb,
            unsigned short* __restrict__ zhi, unsigned short* __restrict__ ehi,
            float* __restrict__ znorm, float* __restrict__ sabs, float* __restrict__ out) {
    __shared__ float tile[64][65];
    __shared__ double reds[256], redsa[256];
    int t = threadIdx.x;
    if (blockIdx.x == 0 && t == 0) out[LOSS_OFF] = 0.f;
    int q0 = blockIdx.x * 64;
    int base = ((q0 >> 12) << 18) + (q0 & 4095);
    int qo = t & 63, dp = t >> 6;
#pragma unroll
    for (int dd = 0; dd < 16; ++dd) {
        int d = dd * 4 + dp;
        tile[d][qo] = z[base + (d << 12) + qo];
    }
    __syncthreads();
    // zhi writes: 512 units = 64 queries x 8 (kc,lh) groups; thread t does units t, t+256.
    size_t ztbase = (size_t)q0 * 64;   // = (q0/32)*2048
#pragma unroll
    for (int uu = 0; uu < 2; ++uu) {
        int unit = uu * 256 + t;
        int q = unit & 63;
        int m = unit >> 6;
        short8 sv;
#pragma unroll
        for (int j = 0; j < 8; ++j)
            sv[j] = (short)to_bf16(tile[m * 8 + j][q]);
        int Q = q0 + q;
        *reinterpret_cast<short8*>(zhi + ztbase + (size_t)(q >> 5) * 2048
                                   + (size_t)m * 256 + (size_t)(Q & 31) * 8) = sv;
    }
    // znorm/sabs: 256 threads compute 16-dim fp64 partials, then 4-way combine.
    {
        int q = t & 63, dpp = t >> 6;
        double s = 0.0, sa = 0.0;
#pragma unroll
        for (int k = 0; k < 16; ++k) {
            float v = tile[dpp * 16 + k][q];
            s += (double)v * (double)v;
            sa += fabs((double)v);
        }
        reds[t] = s;
        redsa[t] = sa;
    }
    __syncthreads();
    if (t < 64) {
        double s = ((reds[t] + reds[64 + t]) + (reds[128 + t] + reds[192 + t]));
        double sa = ((redsa[t] + redsa[64 + t]) + (redsa[128 + t] + redsa[192 + t]));
        znorm[q0 + t] = (float)s;
        sabs[q0 + t] = (float)(sa * 1.000001 + 1e-6);   // strict upper bound on sum|z|
    }
    // emb: one 8-dim block per thread; 512 blocks x 256 units = NCODES*8 units
    {
        int u = blockIdx.x * 256 + t;
        int code = u >> 3, db = u & 7;
        const float4* ep = reinterpret_cast<const float4*>(emb + (size_t)code * 64 + db * 8);
        float4 v0 = ep[0], v1 = ep[1];
        float vv[8] = {v0.x, v0.y, v0.z, v0.w, v1.x, v1.y, v1.z, v1.w};
        short8 h8;
#pragma unroll
        for (int j = 0; j < 8; ++j) h8[j] = (short)to_bf16(vv[j]);
        size_t wi = (size_t)(code >> 5) * 2048 + (size_t)(db >> 1) * 512
                  + (size_t)(db & 1) * 256 + (size_t)(code & 31) * 8;
        *reinterpret_cast<short8*>(ehi + wi) = h8;
    }
}

__device__ __forceinline__ unsigned long long pack_min(float f, int idx) {
    unsigned u = __float_as_uint(f);
    unsigned s = (u & 0x80000000u) ? ~u : (u | 0x80000000u);
    return ((unsigned long long)s << 32) | (unsigned)idx;
}

__device__ __forceinline__ float tmax16(float16 a) {   // max3-friendly tree
    float x0 = fmaxf(a[0], fmaxf(a[1], a[2]));
    float x1 = fmaxf(a[3], fmaxf(a[4], a[5]));
    float x2 = fmaxf(a[6], fmaxf(a[7], a[8]));
    float x3 = fmaxf(a[9], fmaxf(a[10], a[11]));
    float x4 = fmaxf(a[12], fmaxf(a[13], a[14]));
    float y0 = fmaxf(x0, fmaxf(x1, x2));
    float y1 = fmaxf(x3, fmaxf(x4, a[15]));
    return fmaxf(y0, y1);
}

// Pass 1: single hi*hi bf16 MFMA; per-64-code chunk maxima -> fp16 round-up,
// buffered in registers (packed pairs), ONE int4 store per query-group at end.
// 4 query-groups x 1 code-tile; grid (64 qblocks, 32 slabs) x 256; full unroll.
__global__ void __launch_bounds__(256, 2)
approx_kernel(const unsigned short* __restrict__ zhi, const unsigned short* __restrict__ ehi,
              unsigned short* __restrict__ chunkmax) {
    int t = threadIdx.x;
    int lane = t & 63;
    int w = t >> 6;
    int qw = blockIdx.x * 512 + w * 128;
    int cbase = blockIdx.y * 512;
    int l31 = lane & 31, lh = lane >> 5;

    short8 qh[4][4];
    {
        size_t qbase = (size_t)qw * 64 + (size_t)lane * 8;
#pragma unroll
        for (int g = 0; g < 4; ++g)
#pragma unroll
            for (int kc = 0; kc < 4; ++kc)
                qh[g][kc] = *(const short8*)(zhi + qbase + g * 2048 + kc * 512);
    }

    unsigned cv0[4], cv1[4], cv2[4], cv3[4];   // packed fp16 pairs, constant-indexed
#pragma unroll
    for (int c64 = 0; c64 < 8; ++c64) {    // 64-code chunk per iter (fully unrolled)
        float m0 = -3.4e38f, m1 = -3.4e38f, m2 = -3.4e38f, m3 = -3.4e38f;
#pragma unroll
        for (int tl = 0; tl < 2; ++tl) {   // 32 codes per tile
            size_t abase = (size_t)(cbase + c64 * 64 + tl * 32) * 64 + (size_t)lane * 8;
            short8 ch[4];
#pragma unroll
            for (int kc = 0; kc < 4; ++kc)
                ch[kc] = *(const short8*)(ehi + abase + kc * 512);
            float16 a0 = (float16)(0.0f), a1 = (float16)(0.0f);
            float16 a2 = (float16)(0.0f), a3 = (float16)(0.0f);
#pragma unroll
            for (int kc = 0; kc < 4; ++kc) {
                a0 = __builtin_amdgcn_mfma_f32_32x32x16_bf16(ch[kc], qh[0][kc], a0, 0, 0, 0);
                a1 = __builtin_amdgcn_mfma_f32_32x32x16_bf16(ch[kc], qh[1][kc], a1, 0, 0, 0);
                a2 = __builtin_amdgcn_mfma_f32_32x32x16_bf16(ch[kc], qh[2][kc], a2, 0, 0, 0);
                a3 = __builtin_amdgcn_mfma_f32_32x32x16_bf16(ch[kc], qh[3][kc], a3, 0, 0, 0);
            }
            m0 = fmaxf(m0, tmax16(a0));
            m1 = fmaxf(m1, tmax16(a1));
            m2 = fmaxf(m2, tmax16(a2));
            m3 = fmaxf(m3, tmax16(a3));
        }
        m0 = fmaxf(m0, __shfl_xor(m0, 32, 64));
        m1 = fmaxf(m1, __shfl_xor(m1, 32, 64));
        m2 = fmaxf(m2, __shfl_xor(m2, 32, 64));
        m3 = fmaxf(m3, __shfl_xor(m3, 32, 64));
        unsigned h0 = (unsigned)f16_ru(m0);
        unsigned h1 = (unsigned)f16_ru(m1);
        unsigned h2 = (unsigned)f16_ru(m2);
        unsigned h3 = (unsigned)f16_ru(m3);
        if ((c64 & 1) == 0) {
            cv0[c64 >> 1] = h0; cv1[c64 >> 1] = h1;
            cv2[c64 >> 1] = h2; cv3[c64 >> 1] = h3;
        } else {
            cv0[c64 >> 1] |= h0 << 16; cv1[c64 >> 1] |= h1 << 16;
            cv2[c64 >> 1] |= h2 << 16; cv3[c64 >> 1] |= h3 << 16;
        }
    }
    if (lh == 0) {   // one 16B store per query-group: chunks by*8..by*8+7 for query qw+g*32+l31
        size_t coff = (size_t)blockIdx.y * 8;
        *reinterpret_cast<int4*>(chunkmax + (size_t)(qw + l31) * 256 + coff) =
            make_int4((int)cv0[0], (int)cv0[1], (int)cv0[2], (int)cv0[3]);
        *reinterpret_cast<int4*>(chunkmax + (size_t)(qw + 32 + l31) * 256 + coff) =
            make_int4((int)cv1[0], (int)cv1[1], (int)cv1[2], (int)cv1[3]);
        *reinterpret_cast<int4*>(chunkmax + (size_t)(qw + 64 + l31) * 256 + coff) =
            make_int4((int)cv2[0], (int)cv2[1], (int)cv2[2], (int)cv2[3]);
        *reinterpret_cast<int4*>(chunkmax + (size_t)(qw + 96 + l31) * 256 + coff) =
            make_int4((int)cv3[0], (int)cv3[1], (int)cv3[2], (int)cv3[3]);
    }
}

// pop next qualifying chunk id (wave-uniform masks) or -1
#define POPNEXT(c) {                                                            \
    if (m0q) { c = __ffsll((long long)m0q) - 1; m0q &= m0q - 1; }               \
    else if (m1q) { c = 64 + __ffsll((long long)m1q) - 1; m1q &= m1q - 1; }     \
    else if (m2q) { c = 128 + __ffsll((long long)m2q) - 1; m2q &= m2q - 1; }    \
    else if (m3q) { c = 192 + __ffsll((long long)m3q) - 1; m3q &= m3q - 1; }    \
    else c = -1; }

// exact numpy-SSE 16-elem group: code elems Ea..Ed, query floats qp[qo..qo+3]
#define SGROUP(Ea, Eb, Ec, Ed, qo)                                              \
    g0 = qp[qo]; g1 = qp[qo + 1]; g2 = qp[qo + 2]; g3 = qp[qo + 3];             \
    A0 = Ea.x * g0.x + (Eb.x * g1.x + (Ec.x * g2.x + (Ed.x * g3.x + A0)));      \
    A1 = Ea.y * g0.y + (Eb.y * g1.y + (Ec.y * g2.y + (Ed.y * g3.y + A1)));      \
    A2 = Ea.z * g0.z + (Eb.z * g1.z + (Ec.z * g2.z + (Ed.z * g3.z + A2)));      \
    A3 = Ea.w * g0.w + (Eb.w * g1.w + (Ec.w * g2.w + (Ed.w * g3.w + A3)));

// exact SSE distance from E0..E15 into DRES
#define COMPUTE_D(DRES) {                                                       \
    _Pragma("clang fp contract(off)")                                           \
    float A0 = 0.f, A1 = 0.f, A2 = 0.f, A3 = 0.f;                               \
    float4 g0, g1, g2, g3;                                                      \
    SGROUP(E0, E1, E2, E3, 0)                                                   \
    SGROUP(E4, E5, E6, E7, 4)                                                   \
    SGROUP(E8, E9, E10, E11, 8)                                                 \
    SGROUP(E12, E13, E14, E15, 12)                                              \
    float dot = (A0 + A1) + (A2 + A3);   /* SSE3 hadd order */                  \
    DRES = zn - (dot + dot);             /* fl(znorm - 2*dot) */                \
}

// Stage chunk C (16 KB, 64 codes x 16 f4) into this wave's padded LDS region.
#define STAGE_CHUNK(C)                                                          \
    _Pragma("unroll")                                                           \
    for (int j = 0; j < 16; ++j) {                                              \
        int g = j * 64 + lane;                                                  \
        float4 v = emb4[(size_t)(C) * 1024 + g];                                \
        mye[(g >> 4) * 17 + (g & 15)] = v;                                      \
    }

#define READ_ROW {                                                              \
    const float4* rp = mye + lane * 17;                                         \
    E0 = rp[0];  E1 = rp[1];  E2 = rp[2];  E3 = rp[3];                          \
    E4 = rp[4];  E5 = rp[5];  E6 = rp[6];  E7 = rp[7];                          \
    E8 = rp[8];  E9 = rp[9];  E10 = rp[10]; E11 = rp[11];                       \
    E12 = rp[12]; E13 = rp[13]; E14 = rp[14]; E15 = rp[15]; }

// Pass 2: one wave per query, 128-thread blocks (2 waves). Exact-scan the argmax
// chunk first -> D; D-anchored threshold; LDS-staged exact scans of remaining
// qualifying chunks.
__global__ void __launch_bounds__(128, 2)
rescore_kernel(const float* __restrict__ z, const float* __restrict__ emb,
               const float* __restrict__ znorm, const float* __restrict__ sabs,
               const unsigned short* __restrict__ chunkmax,
               unsigned long long* __restrict__ best) {
    __shared__ float lds_q[2 * 64];
    __shared__ float4 lds_e[2 * 64 * 17];   // per wave: 64 rows x (16 f4 + 1 pad)
    int t = threadIdx.x;
    int lane = t & 63;
    int w = t >> 6;
    int qb = blockIdx.x * 2;
    int q = qb + w;

    if (t < 64) {   // queries qb, qb+1 are adjacent floats in z (same d-plane)
        int base0 = ((qb >> 12) << 18) + (qb & 4095);
        float2 vv = *reinterpret_cast<const float2*>(z + base0 + (t << 12));
        lds_q[t] = vv.x;
        lds_q[64 + t] = vv.y;
    }
    __syncthreads();

    float zn = znorm[q];
    float sa = sabs[q];

    const unsigned short* cmq = chunkmax + (size_t)q * 256;
    float ca = __half2float(__ushort_as_half(cmq[lane]));
    float cb = __half2float(__ushort_as_half(cmq[64 + lane]));
    float cc2 = __half2float(__ushort_as_half(cmq[128 + lane]));
    float cd = __half2float(__ushort_as_half(cmq[192 + lane]));
    float m = fmaxf(fmaxf(ca, cb), fmaxf(cc2, cd));
#pragma unroll
    for (int k = 32; k > 0; k >>= 1) m = fmaxf(m, __shfl_xor(m, k, 64));

    // locate one chunk achieving m
    unsigned long long ba = __ballot(ca == m);
    unsigned long long bb = __ballot(cb == m);
    unsigned long long bc = __ballot(cc2 == m);
    unsigned long long bd = __ballot(cd == m);
    int cm_id;
    if (ba) cm_id = __ffsll((long long)ba) - 1;
    else if (bb) cm_id = 64 + __ffsll((long long)bb) - 1;
    else if (bc) cm_id = 128 + __ffsll((long long)bc) - 1;
    else cm_id = 192 + __ffsll((long long)bd) - 1;

    const float4* qp = reinterpret_cast<const float4*>(lds_q + w * 64);
    const float4* emb4 = reinterpret_cast<const float4*>(emb);
    float4* mye = lds_e + w * (64 * 17);

    unsigned long long bloc;
    float4 E0,E1,E2,E3,E4,E5,E6,E7,E8,E9,E10,E11,E12,E13,E14,E15;

    // exact scan of the argmax chunk -> D
    float dmin;
    {
        STAGE_CHUNK(cm_id)
        READ_ROW
        float dres;
        COMPUTE_D(dres)
        bloc = pack_min(dres, cm_id * 64 + lane);
        dmin = dres;
#pragma unroll
        for (int k = 32; k > 0; k >>= 1) dmin = fminf(dmin, __shfl_xor(dmin, k, 64));
    }

    unsigned zb = __float_as_uint(zn);
    int ex = (int)((zb >> 23) & 0xFF);
    float g = __uint_as_float((unsigned)(ex - 23) << 23);   // ulp(zn)
    // D-anchored: t_j >= 0.5(zn-D) - g/2 for any possible winner; E <= 3e-7*sum|z|
    float thr = 0.5f * (zn - dmin) - 0.5f * g - 3e-7f * sa - 2e-6f;

    unsigned long long m0q = __ballot(ca >= thr);
    unsigned long long m1q = __ballot(cb >= thr);
    unsigned long long m2q = __ballot(cc2 >= thr);
    unsigned long long m3q = __ballot(cd >= thr);
    // exclude the already-scanned argmax chunk
    if (cm_id < 64)       m0q &= ~(1ull << cm_id);
    else if (cm_id < 128) m1q &= ~(1ull << (cm_id - 64));
    else if (cm_id < 192) m2q &= ~(1ull << (cm_id - 128));
    else                  m3q &= ~(1ull << (cm_id - 192));

    int cc; POPNEXT(cc);
    while (cc >= 0) {
        STAGE_CHUNK(cc)
        READ_ROW
        float dres;
        COMPUTE_D(dres)
        unsigned long long p = pack_min(dres, cc * 64 + lane);
        if (p < bloc) bloc = p;
        POPNEXT(cc);
    }

#pragma unroll
    for (int k = 32; k > 0; k >>= 1) {
        unsigned long long o = __shfl_xor(bloc, k, 64);
        if (o < bloc) bloc = o;
    }
    if (lane == 0) best[q] = bloc;
}

// Finalize, fully coalesced: 64 queries/block. Wave-parallel emb row gather
// -> padded LDS; transpose-style write phase (thread = query, d-loop).
__global__ void __launch_bounds__(256)
finalize_kernel(const float* __restrict__ z, const float* __restrict__ emb,
                const unsigned long long* __restrict__ best,
                float* __restrict__ out) {
    __shared__ float tile[64][65];   // [q-local][d]
    __shared__ int idxs[64];
    __shared__ float red[256];
    int t = threadIdx.x;
    int lane = t & 63, w = t >> 6;
    int q0 = blockIdx.x * 64;

    if (t < 64) {
        int idx = (int)(unsigned)(best[q0 + t] & 0xFFFFFFFFull) & (NCODES - 1);
        idxs[t] = idx;
        out[IDX_OFF + q0 + t] = (float)idx;
    }
    __syncthreads();
#pragma unroll
    for (int rr = 0; rr < 16; ++rr) {
        int r = rr * 4 + w;
        tile[r][lane] = emb[(size_t)idxs[r] * 64 + lane];
    }
    __syncthreads();
    int base = ((q0 >> 12) << 18) + (q0 & 4095);
    int qo = t & 63, dp = t >> 6;
    float ls = 0.f;
#pragma unroll
    for (int dd = 0; dd < 16; ++dd) {
        int d = dd * 4 + dp;
        float ev = tile[qo][d];
        float zv = z[base + (d << 12) + qo];
        float r = ev - zv;
        ls += r * r;
        out[base + (d << 12) + qo] = ev;
    }
    red[t] = ls;
    __syncthreads();
    for (int off = 128; off > 0; off >>= 1) {
        if (t < off) red[t] += red[t + off];
        __syncthreads();
    }
    if (t == 0) atomicAdd(&out[LOSS_OFF], red[0] * (1.25f / 2097152.f));
}

extern "C" void kernel_launch(void* const* d_in, const int* in_sizes, int n_in,
                              void* d_out, int out_size, void* d_ws, size_t ws_size,
                              hipStream_t stream) {
    const float* z = (const float*)d_in[0];
    const float* emb = (const float*)d_in[1];
    float* out = (float*)d_out;

    char* ws = (char*)d_ws;
    unsigned long long* best = (unsigned long long*)ws;                 // 256 KB @0
    float* znorm = (float*)(ws + 262144);                               // 128 KB
    float* sabs = (float*)(ws + 393216);                                // 128 KB
    unsigned short* chunkmax = (unsigned short*)(ws + 524288);          // 16 MB fp16 [q][256]
    unsigned short* zhi = (unsigned short*)(ws + 17301504);             // 4 MB (swizzled)
    unsigned short* ehi = (unsigned short*)(ws + 21495808);             // 2 MB (total ~23.6 MB)

    prep_kernel<<<NQ / 64, 256, 0, stream>>>(z, emb, zhi, ehi, znorm, sabs, out);
    approx_kernel<<<dim3(64, 32), 256, 0, stream>>>(zhi, ehi, chunkmax);
    rescore_kernel<<<NQ / 2, 128, 0, stream>>>(z, emb, znorm, sabs, chunkmax, best);
    finalize_kernel<<<NQ / 64, 256, 0, stream>>>(z, emb, best, out);
}

// Round 23
// 204.842 us; speedup vs baseline: 1.0576x; 1.0096x over previous
//
#include <hip/hip_runtime.h>
#include <hip/hip_fp16.h>

#define NQ 32768           // total queries = 8192 positions * K=4
#define NCODES 16384
#define ZQ_ELEMS 2097152   // 8*256*32*32
#define IDX_OFF ZQ_ELEMS
#define LOSS_OFF (ZQ_ELEMS + NQ)
// 256 chunks of 64 codes each; chunkmax: fp16 (round-up) [query][256] = 16 MB
// bf16 buffers in MFMA-fragment order: [tile=row/32][kc=d/16][lh=(d>>3)&1][l31=row&31][j=d&7]

typedef __attribute__((ext_vector_type(8))) short short8;
typedef __attribute__((ext_vector_type(16))) float float16;

// query id j = b*4096 + i*1024 + hw ; z element (j,d) at (b<<18) + (d<<12) + (i<<10) + hw

__device__ __forceinline__ unsigned short to_bf16(float v) {
    unsigned u = __float_as_uint(v);
    u = u + 0x7FFFu + ((u >> 16) & 1u);          // round-to-nearest-even
    return (unsigned short)(u >> 16);
}

// f32 -> f16 bits, rounded UP (result as float >= x).
__device__ __forceinline__ unsigned short f16_ru(float x) {
    __half h = __float2half(x);                  // RNE
    unsigned short u = __half_as_ushort(h);
    if (__half2float(h) < x) {
        if (u & 0x8000) u = (u == 0x8000) ? (unsigned short)0x0001 : (unsigned short)(u - 1);
        else u = (unsigned short)(u + 1);
    }
    return u;
}

// Fused prep: z transpose -> swizzled bf16 hi (coalesced short8 stores),
// znorm + sum|z| (parallel fp64 partials), emb -> swizzled bf16 hi.
__global__ void __launch_bounds__(256)
prep_kernel(const float* __restrict__ z, const float* __restrict__ emb,
            unsigned short* __restrict__ zhi, unsigned short* __restrict__ ehi,
            float* __restrict__ znorm, float* __restrict__ sabs, float* __restrict__ out) {
    __shared__ float tile[64][65];
    __shared__ double reds[256], redsa[256];
    int t = threadIdx.x;
    if (blockIdx.x == 0 && t == 0) out[LOSS_OFF] = 0.f;
    int q0 = blockIdx.x * 64;
    int base = ((q0 >> 12) << 18) + (q0 & 4095);
    int qo = t & 63, dp = t >> 6;
#pragma unroll
    for (int dd = 0; dd < 16; ++dd) {
        int d = dd * 4 + dp;
        tile[d][qo] = z[base + (d << 12) + qo];
    }
    __syncthreads();
    // zhi writes: 512 units = 64 queries x 8 (kc,lh) groups; thread t does units t, t+256.
    size_t ztbase = (size_t)q0 * 64;   // = (q0/32)*2048
#pragma unroll
    for (int uu = 0; uu < 2; ++uu) {
        int unit = uu * 256 + t;
        int q = unit & 63;
        int m = unit >> 6;
        short8 sv;
#pragma unroll
        for (int j = 0; j < 8; ++j)
            sv[j] = (short)to_bf16(tile[m * 8 + j][q]);
        int Q = q0 + q;
        *reinterpret_cast<short8*>(zhi + ztbase + (size_t)(q >> 5) * 2048
                                   + (size_t)m * 256 + (size_t)(Q & 31) * 8) = sv;
    }
    // znorm/sabs: 256 threads compute 16-dim fp64 partials, then 4-way combine.
    {
        int q = t & 63, dpp = t >> 6;
        double s = 0.0, sa = 0.0;
#pragma unroll
        for (int k = 0; k < 16; ++k) {
            float v = tile[dpp * 16 + k][q];
            s += (double)v * (double)v;
            sa += fabs((double)v);
        }
        reds[t] = s;
        redsa[t] = sa;
    }
    __syncthreads();
    if (t < 64) {
        double s = ((reds[t] + reds[64 + t]) + (reds[128 + t] + reds[192 + t]));
        double sa = ((redsa[t] + redsa[64 + t]) + (redsa[128 + t] + redsa[192 + t]));
        znorm[q0 + t] = (float)s;
        sabs[q0 + t] = (float)(sa * 1.000001 + 1e-6);   // strict upper bound on sum|z|
    }
    // emb: one 8-dim block per thread; 512 blocks x 256 units = NCODES*8 units
    {
        int u = blockIdx.x * 256 + t;
        int code = u >> 3, db = u & 7;
        const float4* ep = reinterpret_cast<const float4*>(emb + (size_t)code * 64 + db * 8);
        float4 v0 = ep[0], v1 = ep[1];
        float vv[8] = {v0.x, v0.y, v0.z, v0.w, v1.x, v1.y, v1.z, v1.w};
        short8 h8;
#pragma unroll
        for (int j = 0; j < 8; ++j) h8[j] = (short)to_bf16(vv[j]);
        size_t wi = (size_t)(code >> 5) * 2048 + (size_t)(db >> 1) * 512
                  + (size_t)(db & 1) * 256 + (size_t)(code & 31) * 8;
        *reinterpret_cast<short8*>(ehi + wi) = h8;
    }
}

__device__ __forceinline__ unsigned long long pack_min(float f, int idx) {
    unsigned u = __float_as_uint(f);
    unsigned s = (u & 0x80000000u) ? ~u : (u | 0x80000000u);
    return ((unsigned long long)s << 32) | (unsigned)idx;
}

__device__ __forceinline__ float tmax16(float16 a) {   // max3-friendly tree
    float x0 = fmaxf(a[0], fmaxf(a[1], a[2]));
    float x1 = fmaxf(a[3], fmaxf(a[4], a[5]));
    float x2 = fmaxf(a[6], fmaxf(a[7], a[8]));
    float x3 = fmaxf(a[9], fmaxf(a[10], a[11]));
    float x4 = fmaxf(a[12], fmaxf(a[13], a[14]));
    float y0 = fmaxf(x0, fmaxf(x1, x2));
    float y1 = fmaxf(x3, fmaxf(x4, a[15]));
    return fmaxf(y0, y1);
}

// Pass 1: single hi*hi bf16 MFMA; per-64-code chunk maxima -> fp16 round-up,
// buffered in registers (packed pairs), ONE int4 store per query-group at end.
// 4 query-groups x 1 code-tile; grid (64 qblocks, 32 slabs) x 256; full unroll.
__global__ void __launch_bounds__(256, 2)
approx_kernel(const unsigned short* __restrict__ zhi, const unsigned short* __restrict__ ehi,
              unsigned short* __restrict__ chunkmax) {
    int t = threadIdx.x;
    int lane = t & 63;
    int w = t >> 6;
    int qw = blockIdx.x * 512 + w * 128;
    int cbase = blockIdx.y * 512;
    int l31 = lane & 31, lh = lane >> 5;

    short8 qh[4][4];
    {
        size_t qbase = (size_t)qw * 64 + (size_t)lane * 8;
#pragma unroll
        for (int g = 0; g < 4; ++g)
#pragma unroll
            for (int kc = 0; kc < 4; ++kc)
                qh[g][kc] = *(const short8*)(zhi + qbase + g * 2048 + kc * 512);
    }

    unsigned cv0[4], cv1[4], cv2[4], cv3[4];   // packed fp16 pairs, constant-indexed
#pragma unroll
    for (int c64 = 0; c64 < 8; ++c64) {    // 64-code chunk per iter (fully unrolled)
        float m0 = -3.4e38f, m1 = -3.4e38f, m2 = -3.4e38f, m3 = -3.4e38f;
#pragma unroll
        for (int tl = 0; tl < 2; ++tl) {   // 32 codes per tile
            size_t abase = (size_t)(cbase + c64 * 64 + tl * 32) * 64 + (size_t)lane * 8;
            short8 ch[4];
#pragma unroll
            for (int kc = 0; kc < 4; ++kc)
                ch[kc] = *(const short8*)(ehi + abase + kc * 512);
            float16 a0 = (float16)(0.0f), a1 = (float16)(0.0f);
            float16 a2 = (float16)(0.0f), a3 = (float16)(0.0f);
#pragma unroll
            for (int kc = 0; kc < 4; ++kc) {
                a0 = __builtin_amdgcn_mfma_f32_32x32x16_bf16(ch[kc], qh[0][kc], a0, 0, 0, 0);
                a1 = __builtin_amdgcn_mfma_f32_32x32x16_bf16(ch[kc], qh[1][kc], a1, 0, 0, 0);
                a2 = __builtin_amdgcn_mfma_f32_32x32x16_bf16(ch[kc], qh[2][kc], a2, 0, 0, 0);
                a3 = __builtin_amdgcn_mfma_f32_32x32x16_bf16(ch[kc], qh[3][kc], a3, 0, 0, 0);
            }
            m0 = fmaxf(m0, tmax16(a0));
            m1 = fmaxf(m1, tmax16(a1));
            m2 = fmaxf(m2, tmax16(a2));
            m3 = fmaxf(m3, tmax16(a3));
        }
        m0 = fmaxf(m0, __shfl_xor(m0, 32, 64));
        m1 = fmaxf(m1, __shfl_xor(m1, 32, 64));
        m2 = fmaxf(m2, __shfl_xor(m2, 32, 64));
        m3 = fmaxf(m3, __shfl_xor(m3, 32, 64));
        unsigned h0 = (unsigned)f16_ru(m0);
        unsigned h1 = (unsigned)f16_ru(m1);
        unsigned h2 = (unsigned)f16_ru(m2);
        unsigned h3 = (unsigned)f16_ru(m3);
        if ((c64 & 1) == 0) {
            cv0[c64 >> 1] = h0; cv1[c64 >> 1] = h1;
            cv2[c64 >> 1] = h2; cv3[c64 >> 1] = h3;
        } else {
            cv0[c64 >> 1] |= h0 << 16; cv1[c64 >> 1] |= h1 << 16;
            cv2[c64 >> 1] |= h2 << 16; cv3[c64 >> 1] |= h3 << 16;
        }
    }
    if (lh == 0) {   // one 16B store per query-group: chunks by*8..by*8+7
        size_t coff = (size_t)blockIdx.y * 8;
        *reinterpret_cast<int4*>(chunkmax + (size_t)(qw + l31) * 256 + coff) =
            make_int4((int)cv0[0], (int)cv0[1], (int)cv0[2], (int)cv0[3]);
        *reinterpret_cast<int4*>(chunkmax + (size_t)(qw + 32 + l31) * 256 + coff) =
            make_int4((int)cv1[0], (int)cv1[1], (int)cv1[2], (int)cv1[3]);
        *reinterpret_cast<int4*>(chunkmax + (size_t)(qw + 64 + l31) * 256 + coff) =
            make_int4((int)cv2[0], (int)cv2[1], (int)cv2[2], (int)cv2[3]);
        *reinterpret_cast<int4*>(chunkmax + (size_t)(qw + 96 + l31) * 256 + coff) =
            make_int4((int)cv3[0], (int)cv3[1], (int)cv3[2], (int)cv3[3]);
    }
}

// pop next qualifying chunk id (wave-uniform masks) or -1
#define POPNEXT(c) {                                                            \
    if (m0q) { c = __ffsll((long long)m0q) - 1; m0q &= m0q - 1; }               \
    else if (m1q) { c = 64 + __ffsll((long long)m1q) - 1; m1q &= m1q - 1; }     \
    else if (m2q) { c = 128 + __ffsll((long long)m2q) - 1; m2q &= m2q - 1; }    \
    else if (m3q) { c = 192 + __ffsll((long long)m3q) - 1; m3q &= m3q - 1; }    \
    else c = -1; }

// exact numpy-SSE 16-elem group: code elems Ea..Ed, query floats qp[qo..qo+3]
#define SGROUP(Ea, Eb, Ec, Ed, qo)                                              \
    g0 = qp[qo]; g1 = qp[qo + 1]; g2 = qp[qo + 2]; g3 = qp[qo + 3];             \
    A0 = Ea.x * g0.x + (Eb.x * g1.x + (Ec.x * g2.x + (Ed.x * g3.x + A0)));      \
    A1 = Ea.y * g0.y + (Eb.y * g1.y + (Ec.y * g2.y + (Ed.y * g3.y + A1)));      \
    A2 = Ea.z * g0.z + (Eb.z * g1.z + (Ec.z * g2.z + (Ed.z * g3.z + A2)));      \
    A3 = Ea.w * g0.w + (Eb.w * g1.w + (Ec.w * g2.w + (Ed.w * g3.w + A3)));

// exact SSE distance from E0..E15 into DRES
#define COMPUTE_D(DRES) {                                                       \
    _Pragma("clang fp contract(off)")                                           \
    float A0 = 0.f, A1 = 0.f, A2 = 0.f, A3 = 0.f;                               \
    float4 g0, g1, g2, g3;                                                      \
    SGROUP(E0, E1, E2, E3, 0)                                                   \
    SGROUP(E4, E5, E6, E7, 4)                                                   \
    SGROUP(E8, E9, E10, E11, 8)                                                 \
    SGROUP(E12, E13, E14, E15, 12)                                              \
    float dot = (A0 + A1) + (A2 + A3);   /* SSE3 hadd order */                  \
    DRES = zn - (dot + dot);             /* fl(znorm - 2*dot) */                \
}

// Stage chunk C (16 KB, 64 codes x 16 f4) into XOR-swizzled LDS:
// slot(r,c) = r*16 + (c ^ (r&15)). Same 8-round bank pattern as padding,
// but 16 KB/wave instead of 17.1 -> 9 blocks/CU at 1 wave/block.
#define STAGE_CHUNK(C)                                                          \
    _Pragma("unroll")                                                           \
    for (int j = 0; j < 16; ++j) {                                              \
        int g = j * 64 + lane;                                                  \
        float4 v = emb4[(size_t)(C) * 1024 + g];                                \
        int r = g >> 4, c = g & 15;                                             \
        mye[r * 16 + (c ^ (r & 15))] = v;                                       \
    }

#define READ_ROW {                                                              \
    const int rb = lane * 16, rx = lane & 15;                                   \
    E0 = mye[rb + (0 ^ rx)];   E1 = mye[rb + (1 ^ rx)];                         \
    E2 = mye[rb + (2 ^ rx)];   E3 = mye[rb + (3 ^ rx)];                         \
    E4 = mye[rb + (4 ^ rx)];   E5 = mye[rb + (5 ^ rx)];                         \
    E6 = mye[rb + (6 ^ rx)];   E7 = mye[rb + (7 ^ rx)];                         \
    E8 = mye[rb + (8 ^ rx)];   E9 = mye[rb + (9 ^ rx)];                         \
    E10 = mye[rb + (10 ^ rx)]; E11 = mye[rb + (11 ^ rx)];                       \
    E12 = mye[rb + (12 ^ rx)]; E13 = mye[rb + (13 ^ rx)];                       \
    E14 = mye[rb + (14 ^ rx)]; E15 = mye[rb + (15 ^ rx)]; }

// Pass 2: ONE 64-thread block (one wave) per query. Exact-scan the argmax chunk
// first -> D; D-anchored threshold; LDS-staged exact scans of remaining chunks.
__global__ void __launch_bounds__(64, 2)
rescore_kernel(const float* __restrict__ z, const float* __restrict__ emb,
               const float* __restrict__ znorm, const float* __restrict__ sabs,
               const unsigned short* __restrict__ chunkmax,
               unsigned long long* __restrict__ best) {
    __shared__ float lds_q[64];
    __shared__ float4 lds_e[64 * 16];   // 16 KB, XOR-swizzled
    int lane = threadIdx.x;
    int q = blockIdx.x;
    int base0 = ((q >> 12) << 18) + (q & 4095);

    lds_q[lane] = z[base0 + (lane << 12)];
    __syncthreads();

    float zn = znorm[q];
    float sa = sabs[q];

    const unsigned short* cmq = chunkmax + (size_t)q * 256;
    float ca = __half2float(__ushort_as_half(cmq[lane]));
    float cb = __half2float(__ushort_as_half(cmq[64 + lane]));
    float cc2 = __half2float(__ushort_as_half(cmq[128 + lane]));
    float cd = __half2float(__ushort_as_half(cmq[192 + lane]));
    float m = fmaxf(fmaxf(ca, cb), fmaxf(cc2, cd));
#pragma unroll
    for (int k = 32; k > 0; k >>= 1) m = fmaxf(m, __shfl_xor(m, k, 64));

    // locate one chunk achieving m
    unsigned long long ba = __ballot(ca == m);
    unsigned long long bb = __ballot(cb == m);
    unsigned long long bc = __ballot(cc2 == m);
    unsigned long long bd = __ballot(cd == m);
    int cm_id;
    if (ba) cm_id = __ffsll((long long)ba) - 1;
    else if (bb) cm_id = 64 + __ffsll((long long)bb) - 1;
    else if (bc) cm_id = 128 + __ffsll((long long)bc) - 1;
    else cm_id = 192 + __ffsll((long long)bd) - 1;

    const float4* qp = reinterpret_cast<const float4*>(lds_q);
    const float4* emb4 = reinterpret_cast<const float4*>(emb);
    float4* mye = lds_e;

    unsigned long long bloc;
    float4 E0,E1,E2,E3,E4,E5,E6,E7,E8,E9,E10,E11,E12,E13,E14,E15;

    // exact scan of the argmax chunk -> D
    float dmin;
    {
        STAGE_CHUNK(cm_id)
        READ_ROW
        float dres;
        COMPUTE_D(dres)
        bloc = pack_min(dres, cm_id * 64 + lane);
        dmin = dres;
#pragma unroll
        for (int k = 32; k > 0; k >>= 1) dmin = fminf(dmin, __shfl_xor(dmin, k, 64));
    }

    unsigned zb = __float_as_uint(zn);
    int ex = (int)((zb >> 23) & 0xFF);
    float g = __uint_as_float((unsigned)(ex - 23) << 23);   // ulp(zn)
    // D-anchored: t_j >= 0.5(zn-D) - g/2 for any possible winner; E <= 3e-7*sum|z|
    float thr = 0.5f * (zn - dmin) - 0.5f * g - 3e-7f * sa - 2e-6f;

    unsigned long long m0q = __ballot(ca >= thr);
    unsigned long long m1q = __ballot(cb >= thr);
    unsigned long long m2q = __ballot(cc2 >= thr);
    unsigned long long m3q = __ballot(cd >= thr);
    // exclude the already-scanned argmax chunk
    if (cm_id < 64)       m0q &= ~(1ull << cm_id);
    else if (cm_id < 128) m1q &= ~(1ull << (cm_id - 64));
    else if (cm_id < 192) m2q &= ~(1ull << (cm_id - 128));
    else                  m3q &= ~(1ull << (cm_id - 192));

    int cc; POPNEXT(cc);
    while (cc >= 0) {
        STAGE_CHUNK(cc)
        READ_ROW
        float dres;
        COMPUTE_D(dres)
        unsigned long long p = pack_min(dres, cc * 64 + lane);
        if (p < bloc) bloc = p;
        POPNEXT(cc);
    }

#pragma unroll
    for (int k = 32; k > 0; k >>= 1) {
        unsigned long long o = __shfl_xor(bloc, k, 64);
        if (o < bloc) bloc = o;
    }
    if (lane == 0) best[q] = bloc;
}

// Finalize, fully coalesced: 64 queries/block. Wave-parallel emb row gather
// -> padded LDS; transpose-style write phase (thread = query, d-loop).
__global__ void __launch_bounds__(256)
finalize_kernel(const float* __restrict__ z, const float* __restrict__ emb,
                const unsigned long long* __restrict__ best,
                float* __restrict__ out) {
    __shared__ float tile[64][65];   // [q-local][d]
    __shared__ int idxs[64];
    __shared__ float red[256];
    int t = threadIdx.x;
    int lane = t & 63, w = t >> 6;
    int q0 = blockIdx.x * 64;

    if (t < 64) {
        int idx = (int)(unsigned)(best[q0 + t] & 0xFFFFFFFFull) & (NCODES - 1);
        idxs[t] = idx;
        out[IDX_OFF + q0 + t] = (float)idx;
    }
    __syncthreads();
#pragma unroll
    for (int rr = 0; rr < 16; ++rr) {
        int r = rr * 4 + w;
        tile[r][lane] = emb[(size_t)idxs[r] * 64 + lane];
    }
    __syncthreads();
    int base = ((q0 >> 12) << 18) + (q0 & 4095);
    int qo = t & 63, dp = t >> 6;
    float ls = 0.f;
#pragma unroll
    for (int dd = 0; dd < 16; ++dd) {
        int d = dd * 4 + dp;
        float ev = tile[qo][d];
        float zv = z[base + (d << 12) + qo];
        float r = ev - zv;
        ls += r * r;
        out[base + (d << 12) + qo] = ev;
    }
    red[t] = ls;
    __syncthreads();
    for (int off = 128; off > 0; off >>= 1) {
        if (t < off) red[t] += red[t + off];
        __syncthreads();
    }
    if (t == 0) atomicAdd(&out[LOSS_OFF], red[0] * (1.25f / 2097152.f));
}

extern "C" void kernel_launch(void* const* d_in, const int* in_sizes, int n_in,
                              void* d_out, int out_size, void* d_ws, size_t ws_size,
                              hipStream_t stream) {
    const float* z = (const float*)d_in[0];
    const float* emb = (const float*)d_in[1];
    float* out = (float*)d_out;

    char* ws = (char*)d_ws;
    unsigned long long* best = (unsigned long long*)ws;                 // 256 KB @0
    float* znorm = (float*)(ws + 262144);                               // 128 KB
    float* sabs = (float*)(ws + 393216);                                // 128 KB
    unsigned short* chunkmax = (unsigned short*)(ws + 524288);          // 16 MB fp16 [q][256]
    unsigned short* zhi = (unsigned short*)(ws + 17301504);             // 4 MB (swizzled)
    unsigned short* ehi = (unsigned short*)(ws + 21495808);             // 2 MB (total ~23.6 MB)

    prep_kernel<<<NQ / 64, 256, 0, stream>>>(z, emb, zhi, ehi, znorm, sabs, out);
    approx_kernel<<<dim3(64, 32), 256, 0, stream>>>(zhi, ehi, chunkmax);
    rescore_kernel<<<NQ, 64, 0, stream>>>(z, emb, znorm, sabs, chunkmax, best);
    finalize_kernel<<<NQ / 64, 256, 0, stream>>>(z, emb, best, out);
}

// Round 24
// 199.900 us; speedup vs baseline: 1.0837x; 1.0247x over previous
//
#include <hip/hip_runtime.h>
#include <hip/hip_fp16.h>

#define NQ 32768           // total queries = 8192 positions * K=4
#define NCODES 16384
#define ZQ_ELEMS 2097152   // 8*256*32*32
#define IDX_OFF ZQ_ELEMS
#define LOSS_OFF (ZQ_ELEMS + NQ)
// 256 chunks of 64 codes each; chunkmax: fp16 (round-up) [query][256] = 16 MB
// bf16 buffers in MFMA-fragment order: [tile=row/32][kc=d/16][lh=(d>>3)&1][l31=row&31][j=d&7]
// zt: optional fp32 transposed z [q][64] (8 MB) if ws_size permits

typedef __attribute__((ext_vector_type(8))) short short8;
typedef __attribute__((ext_vector_type(16))) float float16;

// query id j = b*4096 + i*1024 + hw ; z element (j,d) at (b<<18) + (d<<12) + (i<<10) + hw

__device__ __forceinline__ unsigned short to_bf16(float v) {
    unsigned u = __float_as_uint(v);
    u = u + 0x7FFFu + ((u >> 16) & 1u);          // round-to-nearest-even
    return (unsigned short)(u >> 16);
}

// f32 -> f16 bits, rounded UP (result as float >= x).
__device__ __forceinline__ unsigned short f16_ru(float x) {
    __half h = __float2half(x);                  // RNE
    unsigned short u = __half_as_ushort(h);
    if (__half2float(h) < x) {
        if (u & 0x8000) u = (u == 0x8000) ? (unsigned short)0x0001 : (unsigned short)(u - 1);
        else u = (unsigned short)(u + 1);
    }
    return u;
}

// Fused prep: z transpose -> swizzled bf16 hi + optional fp32 zt copy,
// znorm + sum|z| (parallel fp64 partials), emb -> swizzled bf16 hi.
__global__ void __launch_bounds__(256)
prep_kernel(const float* __restrict__ z, const float* __restrict__ emb,
            unsigned short* __restrict__ zhi, unsigned short* __restrict__ ehi,
            float* __restrict__ znorm, float* __restrict__ sabs,
            float* __restrict__ zt, float* __restrict__ out) {
    __shared__ float tile[64][65];
    __shared__ double reds[256], redsa[256];
    int t = threadIdx.x;
    if (blockIdx.x == 0 && t == 0) out[LOSS_OFF] = 0.f;
    int q0 = blockIdx.x * 64;
    int base = ((q0 >> 12) << 18) + (q0 & 4095);
    int qo = t & 63, dp = t >> 6;
#pragma unroll
    for (int dd = 0; dd < 16; ++dd) {
        int d = dd * 4 + dp;
        tile[d][qo] = z[base + (d << 12) + qo];
    }
    __syncthreads();
    // zhi writes: 512 units = 64 queries x 8 (kc,lh) groups; thread t does units t, t+256.
    size_t ztbase = (size_t)q0 * 64;   // = (q0/32)*2048
#pragma unroll
    for (int uu = 0; uu < 2; ++uu) {
        int unit = uu * 256 + t;
        int q = unit & 63;
        int m = unit >> 6;
        short8 sv;
#pragma unroll
        for (int j = 0; j < 8; ++j)
            sv[j] = (short)to_bf16(tile[m * 8 + j][q]);
        int Q = q0 + q;
        *reinterpret_cast<short8*>(zhi + ztbase + (size_t)(q >> 5) * 2048
                                   + (size_t)m * 256 + (size_t)(Q & 31) * 8) = sv;
    }
    // zt: fp32 transposed z [q][64], fully-coalesced float4 stores
    if (zt) {
        float* ztb = zt + (size_t)q0 * 64;
#pragma unroll
        for (int j = 0; j < 4; ++j) {
            int e = (j * 256 + t) * 4;
            int q = e >> 6, d = e & 63;
            float4 v = make_float4(tile[d][q], tile[d + 1][q], tile[d + 2][q], tile[d + 3][q]);
            *reinterpret_cast<float4*>(ztb + e) = v;
        }
    }
    // znorm/sabs: 256 threads compute 16-dim fp64 partials, then 4-way combine.
    {
        int q = t & 63, dpp = t >> 6;
        double s = 0.0, sa = 0.0;
#pragma unroll
        for (int k = 0; k < 16; ++k) {
            float v = tile[dpp * 16 + k][q];
            s += (double)v * (double)v;
            sa += fabs((double)v);
        }
        reds[t] = s;
        redsa[t] = sa;
    }
    __syncthreads();
    if (t < 64) {
        double s = ((reds[t] + reds[64 + t]) + (reds[128 + t] + reds[192 + t]));
        double sa = ((redsa[t] + redsa[64 + t]) + (redsa[128 + t] + redsa[192 + t]));
        znorm[q0 + t] = (float)s;
        sabs[q0 + t] = (float)(sa * 1.000001 + 1e-6);   // strict upper bound on sum|z|
    }
    // emb: one 8-dim block per thread; 512 blocks x 256 units = NCODES*8 units
    {
        int u = blockIdx.x * 256 + t;
        int code = u >> 3, db = u & 7;
        const float4* ep = reinterpret_cast<const float4*>(emb + (size_t)code * 64 + db * 8);
        float4 v0 = ep[0], v1 = ep[1];
        float vv[8] = {v0.x, v0.y, v0.z, v0.w, v1.x, v1.y, v1.z, v1.w};
        short8 h8;
#pragma unroll
        for (int j = 0; j < 8; ++j) h8[j] = (short)to_bf16(vv[j]);
        size_t wi = (size_t)(code >> 5) * 2048 + (size_t)(db >> 1) * 512
                  + (size_t)(db & 1) * 256 + (size_t)(code & 31) * 8;
        *reinterpret_cast<short8*>(ehi + wi) = h8;
    }
}

__device__ __forceinline__ unsigned long long pack_min(float f, int idx) {
    unsigned u = __float_as_uint(f);
    unsigned s = (u & 0x80000000u) ? ~u : (u | 0x80000000u);
    return ((unsigned long long)s << 32) | (unsigned)idx;
}

__device__ __forceinline__ float tmax16(float16 a) {   // max3-friendly tree
    float x0 = fmaxf(a[0], fmaxf(a[1], a[2]));
    float x1 = fmaxf(a[3], fmaxf(a[4], a[5]));
    float x2 = fmaxf(a[6], fmaxf(a[7], a[8]));
    float x3 = fmaxf(a[9], fmaxf(a[10], a[11]));
    float x4 = fmaxf(a[12], fmaxf(a[13], a[14]));
    float y0 = fmaxf(x0, fmaxf(x1, x2));
    float y1 = fmaxf(x3, fmaxf(x4, a[15]));
    return fmaxf(y0, y1);
}

// Pass 1: single hi*hi bf16 MFMA; per-64-code chunk maxima -> fp16 round-up,
// buffered in registers (packed pairs), ONE int4 store per query-group at end.
// 4 query-groups x 1 code-tile; grid (64 qblocks, 32 slabs) x 256; full unroll.
__global__ void __launch_bounds__(256, 2)
approx_kernel(const unsigned short* __restrict__ zhi, const unsigned short* __restrict__ ehi,
              unsigned short* __restrict__ chunkmax) {
    int t = threadIdx.x;
    int lane = t & 63;
    int w = t >> 6;
    int qw = blockIdx.x * 512 + w * 128;
    int cbase = blockIdx.y * 512;
    int l31 = lane & 31, lh = lane >> 5;

    short8 qh[4][4];
    {
        size_t qbase = (size_t)qw * 64 + (size_t)lane * 8;
#pragma unroll
        for (int g = 0; g < 4; ++g)
#pragma unroll
            for (int kc = 0; kc < 4; ++kc)
                qh[g][kc] = *(const short8*)(zhi + qbase + g * 2048 + kc * 512);
    }

    unsigned cv0[4], cv1[4], cv2[4], cv3[4];   // packed fp16 pairs, constant-indexed
#pragma unroll
    for (int c64 = 0; c64 < 8; ++c64) {    // 64-code chunk per iter (fully unrolled)
        float m0 = -3.4e38f, m1 = -3.4e38f, m2 = -3.4e38f, m3 = -3.4e38f;
#pragma unroll
        for (int tl = 0; tl < 2; ++tl) {   // 32 codes per tile
            size_t abase = (size_t)(cbase + c64 * 64 + tl * 32) * 64 + (size_t)lane * 8;
            short8 ch[4];
#pragma unroll
            for (int kc = 0; kc < 4; ++kc)
                ch[kc] = *(const short8*)(ehi + abase + kc * 512);
            float16 a0 = (float16)(0.0f), a1 = (float16)(0.0f);
            float16 a2 = (float16)(0.0f), a3 = (float16)(0.0f);
#pragma unroll
            for (int kc = 0; kc < 4; ++kc) {
                a0 = __builtin_amdgcn_mfma_f32_32x32x16_bf16(ch[kc], qh[0][kc], a0, 0, 0, 0);
                a1 = __builtin_amdgcn_mfma_f32_32x32x16_bf16(ch[kc], qh[1][kc], a1, 0, 0, 0);
                a2 = __builtin_amdgcn_mfma_f32_32x32x16_bf16(ch[kc], qh[2][kc], a2, 0, 0, 0);
                a3 = __builtin_amdgcn_mfma_f32_32x32x16_bf16(ch[kc], qh[3][kc], a3, 0, 0, 0);
            }
            m0 = fmaxf(m0, tmax16(a0));
            m1 = fmaxf(m1, tmax16(a1));
            m2 = fmaxf(m2, tmax16(a2));
            m3 = fmaxf(m3, tmax16(a3));
        }
        m0 = fmaxf(m0, __shfl_xor(m0, 32, 64));
        m1 = fmaxf(m1, __shfl_xor(m1, 32, 64));
        m2 = fmaxf(m2, __shfl_xor(m2, 32, 64));
        m3 = fmaxf(m3, __shfl_xor(m3, 32, 64));
        unsigned h0 = (unsigned)f16_ru(m0);
        unsigned h1 = (unsigned)f16_ru(m1);
        unsigned h2 = (unsigned)f16_ru(m2);
        unsigned h3 = (unsigned)f16_ru(m3);
        if ((c64 & 1) == 0) {
            cv0[c64 >> 1] = h0; cv1[c64 >> 1] = h1;
            cv2[c64 >> 1] = h2; cv3[c64 >> 1] = h3;
        } else {
            cv0[c64 >> 1] |= h0 << 16; cv1[c64 >> 1] |= h1 << 16;
            cv2[c64 >> 1] |= h2 << 16; cv3[c64 >> 1] |= h3 << 16;
        }
    }
    if (lh == 0) {   // one 16B store per query-group: chunks by*8..by*8+7
        size_t coff = (size_t)blockIdx.y * 8;
        *reinterpret_cast<int4*>(chunkmax + (size_t)(qw + l31) * 256 + coff) =
            make_int4((int)cv0[0], (int)cv0[1], (int)cv0[2], (int)cv0[3]);
        *reinterpret_cast<int4*>(chunkmax + (size_t)(qw + 32 + l31) * 256 + coff) =
            make_int4((int)cv1[0], (int)cv1[1], (int)cv1[2], (int)cv1[3]);
        *reinterpret_cast<int4*>(chunkmax + (size_t)(qw + 64 + l31) * 256 + coff) =
            make_int4((int)cv2[0], (int)cv2[1], (int)cv2[2], (int)cv2[3]);
        *reinterpret_cast<int4*>(chunkmax + (size_t)(qw + 96 + l31) * 256 + coff) =
            make_int4((int)cv3[0], (int)cv3[1], (int)cv3[2], (int)cv3[3]);
    }
}

// pop next qualifying chunk id (wave-uniform masks) or -1
#define POPNEXT(c) {                                                            \
    if (m0q) { c = __ffsll((long long)m0q) - 1; m0q &= m0q - 1; }               \
    else if (m1q) { c = 64 + __ffsll((long long)m1q) - 1; m1q &= m1q - 1; }     \
    else if (m2q) { c = 128 + __ffsll((long long)m2q) - 1; m2q &= m2q - 1; }    \
    else if (m3q) { c = 192 + __ffsll((long long)m3q) - 1; m3q &= m3q - 1; }    \
    else c = -1; }

// exact numpy-SSE 16-elem group: code elems Ea..Ed, query floats qp[qo..qo+3]
#define SGROUP(Ea, Eb, Ec, Ed, qo)                                              \
    g0 = qp[qo]; g1 = qp[qo + 1]; g2 = qp[qo + 2]; g3 = qp[qo + 3];             \
    A0 = Ea.x * g0.x + (Eb.x * g1.x + (Ec.x * g2.x + (Ed.x * g3.x + A0)));      \
    A1 = Ea.y * g0.y + (Eb.y * g1.y + (Ec.y * g2.y + (Ed.y * g3.y + A1)));      \
    A2 = Ea.z * g0.z + (Eb.z * g1.z + (Ec.z * g2.z + (Ed.z * g3.z + A2)));      \
    A3 = Ea.w * g0.w + (Eb.w * g1.w + (Ec.w * g2.w + (Ed.w * g3.w + A3)));

// exact SSE distance from E0..E15 into DRES
#define COMPUTE_D(DRES) {                                                       \
    _Pragma("clang fp contract(off)")                                           \
    float A0 = 0.f, A1 = 0.f, A2 = 0.f, A3 = 0.f;                               \
    float4 g0, g1, g2, g3;                                                      \
    SGROUP(E0, E1, E2, E3, 0)                                                   \
    SGROUP(E4, E5, E6, E7, 4)                                                   \
    SGROUP(E8, E9, E10, E11, 8)                                                 \
    SGROUP(E12, E13, E14, E15, 12)                                              \
    float dot = (A0 + A1) + (A2 + A3);   /* SSE3 hadd order */                  \
    DRES = zn - (dot + dot);             /* fl(znorm - 2*dot) */                \
}

// Stage chunk C (16 KB, 64 codes x 16 f4) into XOR-swizzled LDS:
// slot(r,c) = r*16 + (c ^ (r&15)).
#define STAGE_CHUNK(C)                                                          \
    _Pragma("unroll")                                                           \
    for (int j = 0; j < 16; ++j) {                                              \
        int g = j * 64 + lane;                                                  \
        float4 v = emb4[(size_t)(C) * 1024 + g];                                \
        int r = g >> 4, c = g & 15;                                             \
        mye[r * 16 + (c ^ (r & 15))] = v;                                       \
    }

#define READ_ROW {                                                              \
    const int rb = lane * 16, rx = lane & 15;                                   \
    E0 = mye[rb + (0 ^ rx)];   E1 = mye[rb + (1 ^ rx)];                         \
    E2 = mye[rb + (2 ^ rx)];   E3 = mye[rb + (3 ^ rx)];                         \
    E4 = mye[rb + (4 ^ rx)];   E5 = mye[rb + (5 ^ rx)];                         \
    E6 = mye[rb + (6 ^ rx)];   E7 = mye[rb + (7 ^ rx)];                         \
    E8 = mye[rb + (8 ^ rx)];   E9 = mye[rb + (9 ^ rx)];                         \
    E10 = mye[rb + (10 ^ rx)]; E11 = mye[rb + (11 ^ rx)];                       \
    E12 = mye[rb + (12 ^ rx)]; E13 = mye[rb + (13 ^ rx)];                       \
    E14 = mye[rb + (14 ^ rx)]; E15 = mye[rb + (15 ^ rx)]; }

// Pass 2: ONE 64-thread block (one wave) per query. Coalesced q-load from zt
// when available (4 cache lines vs 64). D-anchored threshold; LDS-staged scans.
__global__ void __launch_bounds__(64, 2)
rescore_kernel(const float* __restrict__ z, const float* __restrict__ emb,
               const float* __restrict__ znorm, const float* __restrict__ sabs,
               const unsigned short* __restrict__ chunkmax,
               const float* __restrict__ zt,
               unsigned long long* __restrict__ best) {
    __shared__ float lds_q[64];
    __shared__ float4 lds_e[64 * 16];   // 16 KB, XOR-swizzled
    int lane = threadIdx.x;
    int q = blockIdx.x;
    int base0 = ((q >> 12) << 18) + (q & 4095);

    if (zt) lds_q[lane] = zt[(size_t)q * 64 + lane];     // coalesced: 4 lines
    else    lds_q[lane] = z[base0 + (lane << 12)];       // fallback: 64 lines
    __syncthreads();

    float zn = znorm[q];
    float sa = sabs[q];

    const unsigned short* cmq = chunkmax + (size_t)q * 256;
    float ca = __half2float(__ushort_as_half(cmq[lane]));
    float cb = __half2float(__ushort_as_half(cmq[64 + lane]));
    float cc2 = __half2float(__ushort_as_half(cmq[128 + lane]));
    float cd = __half2float(__ushort_as_half(cmq[192 + lane]));
    float m = fmaxf(fmaxf(ca, cb), fmaxf(cc2, cd));
#pragma unroll
    for (int k = 32; k > 0; k >>= 1) m = fmaxf(m, __shfl_xor(m, k, 64));

    // locate one chunk achieving m
    unsigned long long ba = __ballot(ca == m);
    unsigned long long bb = __ballot(cb == m);
    unsigned long long bc = __ballot(cc2 == m);
    unsigned long long bd = __ballot(cd == m);
    int cm_id;
    if (ba) cm_id = __ffsll((long long)ba) - 1;
    else if (bb) cm_id = 64 + __ffsll((long long)bb) - 1;
    else if (bc) cm_id = 128 + __ffsll((long long)bc) - 1;
    else cm_id = 192 + __ffsll((long long)bd) - 1;

    const float4* qp = reinterpret_cast<const float4*>(lds_q);
    const float4* emb4 = reinterpret_cast<const float4*>(emb);
    float4* mye = lds_e;

    unsigned long long bloc;
    float4 E0,E1,E2,E3,E4,E5,E6,E7,E8,E9,E10,E11,E12,E13,E14,E15;

    // exact scan of the argmax chunk -> D
    float dmin;
    {
        STAGE_CHUNK(cm_id)
        READ_ROW
        float dres;
        COMPUTE_D(dres)
        bloc = pack_min(dres, cm_id * 64 + lane);
        dmin = dres;
#pragma unroll
        for (int k = 32; k > 0; k >>= 1) dmin = fminf(dmin, __shfl_xor(dmin, k, 64));
    }

    unsigned zb = __float_as_uint(zn);
    int ex = (int)((zb >> 23) & 0xFF);
    float g = __uint_as_float((unsigned)(ex - 23) << 23);   // ulp(zn)
    // D-anchored: t_j >= 0.5(zn-D) - g/2 for any possible winner; E <= 3e-7*sum|z|
    float thr = 0.5f * (zn - dmin) - 0.5f * g - 3e-7f * sa - 2e-6f;

    unsigned long long m0q = __ballot(ca >= thr);
    unsigned long long m1q = __ballot(cb >= thr);
    unsigned long long m2q = __ballot(cc2 >= thr);
    unsigned long long m3q = __ballot(cd >= thr);
    // exclude the already-scanned argmax chunk
    if (cm_id < 64)       m0q &= ~(1ull << cm_id);
    else if (cm_id < 128) m1q &= ~(1ull << (cm_id - 64));
    else if (cm_id < 192) m2q &= ~(1ull << (cm_id - 128));
    else                  m3q &= ~(1ull << (cm_id - 192));

    int cc; POPNEXT(cc);
    while (cc >= 0) {
        STAGE_CHUNK(cc)
        READ_ROW
        float dres;
        COMPUTE_D(dres)
        unsigned long long p = pack_min(dres, cc * 64 + lane);
        if (p < bloc) bloc = p;
        POPNEXT(cc);
    }

#pragma unroll
    for (int k = 32; k > 0; k >>= 1) {
        unsigned long long o = __shfl_xor(bloc, k, 64);
        if (o < bloc) bloc = o;
    }
    if (lane == 0) best[q] = bloc;
}

// Finalize, fully coalesced: 64 queries/block. Wave-parallel emb row gather
// -> padded LDS; transpose-style write phase (thread = query, d-loop).
__global__ void __launch_bounds__(256)
finalize_kernel(const float* __restrict__ z, const float* __restrict__ emb,
                const unsigned long long* __restrict__ best,
                float* __restrict__ out) {
    __shared__ float tile[64][65];   // [q-local][d]
    __shared__ int idxs[64];
    __shared__ float red[256];
    int t = threadIdx.x;
    int lane = t & 63, w = t >> 6;
    int q0 = blockIdx.x * 64;

    if (t < 64) {
        int idx = (int)(unsigned)(best[q0 + t] & 0xFFFFFFFFull) & (NCODES - 1);
        idxs[t] = idx;
        out[IDX_OFF + q0 + t] = (float)idx;
    }
    __syncthreads();
#pragma unroll
    for (int rr = 0; rr < 16; ++rr) {
        int r = rr * 4 + w;
        tile[r][lane] = emb[(size_t)idxs[r] * 64 + lane];
    }
    __syncthreads();
    int base = ((q0 >> 12) << 18) + (q0 & 4095);
    int qo = t & 63, dp = t >> 6;
    float ls = 0.f;
#pragma unroll
    for (int dd = 0; dd < 16; ++dd) {
        int d = dd * 4 + dp;
        float ev = tile[qo][d];
        float zv = z[base + (d << 12) + qo];
        float r = ev - zv;
        ls += r * r;
        out[base + (d << 12) + qo] = ev;
    }
    red[t] = ls;
    __syncthreads();
    for (int off = 128; off > 0; off >>= 1) {
        if (t < off) red[t] += red[t + off];
        __syncthreads();
    }
    if (t == 0) atomicAdd(&out[LOSS_OFF], red[0] * (1.25f / 2097152.f));
}

extern "C" void kernel_launch(void* const* d_in, const int* in_sizes, int n_in,
                              void* d_out, int out_size, void* d_ws, size_t ws_size,
                              hipStream_t stream) {
    const float* z = (const float*)d_in[0];
    const float* emb = (const float*)d_in[1];
    float* out = (float*)d_out;

    char* ws = (char*)d_ws;
    unsigned long long* best = (unsigned long long*)ws;                 // 256 KB @0
    float* znorm = (float*)(ws + 262144);                               // 128 KB
    float* sabs = (float*)(ws + 393216);                                // 128 KB
    unsigned short* chunkmax = (unsigned short*)(ws + 524288);          // 16 MB fp16 [q][256]
    unsigned short* zhi = (unsigned short*)(ws + 17301504);             // 4 MB (swizzled)
    unsigned short* ehi = (unsigned short*)(ws + 21495808);             // 2 MB -> end 23592960
    // optional zt: fp32 [NQ][64] = 8 MB at 23592960 (total ~30.5 MB)
    size_t need = 23592960ull + (size_t)NQ * 64 * 4;
    float* zt = (ws_size >= need) ? (float*)(ws + 23592960) : nullptr;

    prep_kernel<<<NQ / 64, 256, 0, stream>>>(z, emb, zhi, ehi, znorm, sabs, zt, out);
    approx_kernel<<<dim3(64, 32), 256, 0, stream>>>(zhi, ehi, chunkmax);
    rescore_kernel<<<NQ, 64, 0, stream>>>(z, emb, znorm, sabs, chunkmax, zt, best);
    finalize_kernel<<<NQ / 64, 256, 0, stream>>>(z, emb, best, out);
}